// Round 1
// baseline (11145.992 us; speedup 1.0000x reference)
//
#include <hip/hip_runtime.h>

#define N_NODES 100000
#define N_EDGES 3200000
#define IN_CH   384
#define HID     128

// ---------------- degree count ----------------
__global__ void k_count(const int* __restrict__ dst, unsigned* __restrict__ deg, int E) {
    int i = blockIdx.x * blockDim.x + threadIdx.x;
    int stride = gridDim.x * blockDim.x;
    for (; i < E; i += stride) atomicAdd(&deg[dst[i]], 1u);
}

__global__ void k_dis(const unsigned* __restrict__ deg, float* __restrict__ dis, int N) {
    int i = blockIdx.x * blockDim.x + threadIdx.x;
    if (i < N) dis[i] = rsqrtf((float)(deg[i] + 1u));  // +1 self-loop
}

// ---------------- fp32 GEMM: C[M,128] = A[M,K] @ B[K,128] ----------------
// block = 256 threads, tile 64 rows x 128 cols, K-chunk 16
__global__ __launch_bounds__(256) void k_gemm(const float* __restrict__ A,
                                              const float* __restrict__ B,
                                              float* __restrict__ C, int M, int K) {
    __shared__ float As[64][16];
    __shared__ float Bs[16][128];
    const int tid = threadIdx.x;
    const int tx = tid & 15;        // 0..15 -> 8 cols each
    const int ty = tid >> 4;        // 0..15 -> 4 rows each (stride 16)
    const int row0 = blockIdx.x * 64;

    float acc[4][8];
#pragma unroll
    for (int i = 0; i < 4; i++)
#pragma unroll
        for (int j = 0; j < 8; j++) acc[i][j] = 0.f;

    const int lrow = tid >> 2;        // 0..63
    const int lc4  = (tid & 3) * 4;   // 0,4,8,12

    for (int k0 = 0; k0 < K; k0 += 16) {
        // stage A tile [64x16]
        int ar = row0 + lrow;
        float4 av = make_float4(0.f, 0.f, 0.f, 0.f);
        if (ar < M) av = *reinterpret_cast<const float4*>(&A[(size_t)ar * K + k0 + lc4]);
        *reinterpret_cast<float4*>(&As[lrow][lc4]) = av;
        // stage B tile [16x128]: 512 float4s, 2 per thread
#pragma unroll
        for (int t = 0; t < 2; t++) {
            int f4 = tid + t * 256;
            int br = f4 >> 5;
            int bc = (f4 & 31) * 4;
            *reinterpret_cast<float4*>(&Bs[br][bc]) =
                *reinterpret_cast<const float4*>(&B[(size_t)(k0 + br) * 128 + bc]);
        }
        __syncthreads();
#pragma unroll
        for (int kk = 0; kk < 16; kk++) {
            float a[4];
#pragma unroll
            for (int i = 0; i < 4; i++) a[i] = As[ty + i * 16][kk];
            float4 b0 = *reinterpret_cast<const float4*>(&Bs[kk][tx * 8]);
            float4 b1 = *reinterpret_cast<const float4*>(&Bs[kk][tx * 8 + 4]);
            float b[8] = {b0.x, b0.y, b0.z, b0.w, b1.x, b1.y, b1.z, b1.w};
#pragma unroll
            for (int i = 0; i < 4; i++)
#pragma unroll
                for (int j = 0; j < 8; j++) acc[i][j] = fmaf(a[i], b[j], acc[i][j]);
        }
        __syncthreads();
    }
#pragma unroll
    for (int i = 0; i < 4; i++) {
        int r = row0 + ty + i * 16;
        if (r < M) {
            float4 c0 = make_float4(acc[i][0], acc[i][1], acc[i][2], acc[i][3]);
            float4 c1 = make_float4(acc[i][4], acc[i][5], acc[i][6], acc[i][7]);
            *reinterpret_cast<float4*>(&C[(size_t)r * 128 + tx * 8]) = c0;
            *reinterpret_cast<float4*>(&C[(size_t)r * 128 + tx * 8 + 4]) = c1;
        }
    }
}

// ---------------- edge scatter: out[dst] += dis[s]*dis[d] * h[src] ----------------
// 32 lanes per edge, float4 per lane (128 channels)
__global__ __launch_bounds__(256) void k_scatter(const float* __restrict__ h,
                                                 const int* __restrict__ src,
                                                 const int* __restrict__ dst,
                                                 const float* __restrict__ dis,
                                                 float* __restrict__ out, int E) {
    const int lane = threadIdx.x & 31;
    const int grp  = (blockIdx.x * blockDim.x + threadIdx.x) >> 5;
    const int ngrp = (gridDim.x * blockDim.x) >> 5;
    for (int e = grp; e < E; e += ngrp) {
        int s = src[e], d = dst[e];
        float nrm = dis[s] * dis[d];
        float4 v = *reinterpret_cast<const float4*>(&h[(size_t)s * 128 + lane * 4]);
        float* o = &out[(size_t)d * 128 + lane * 4];
        unsafeAtomicAdd(o + 0, nrm * v.x);
        unsafeAtomicAdd(o + 1, nrm * v.y);
        unsafeAtomicAdd(o + 2, nrm * v.z);
        unsafeAtomicAdd(o + 3, nrm * v.w);
    }
}

// ---------------- finalize: out = out + dis^2*h_self + bias [, relu] ----------------
__global__ void k_finalize(const float* __restrict__ hself, const float* __restrict__ dis,
                           const float* __restrict__ bias, float* __restrict__ out,
                           int N, int relu) {
    int i = blockIdx.x * blockDim.x + threadIdx.x;  // over N*32 float4 tasks
    int total = N * 32;
    int stride = gridDim.x * blockDim.x;
    for (; i < total; i += stride) {
        int n = i >> 5, c4 = (i & 31) * 4;
        float dn = dis[n];
        float w = dn * dn;
        float4 hv = *reinterpret_cast<const float4*>(&hself[(size_t)n * 128 + c4]);
        float4 ov = *reinterpret_cast<const float4*>(&out[(size_t)n * 128 + c4]);
        float4 bv = *reinterpret_cast<const float4*>(&bias[c4]);
        float r0 = ov.x + w * hv.x + bv.x;
        float r1 = ov.y + w * hv.y + bv.y;
        float r2 = ov.z + w * hv.z + bv.z;
        float r3 = ov.w + w * hv.w + bv.w;
        if (relu) {
            r0 = fmaxf(r0, 0.f); r1 = fmaxf(r1, 0.f);
            r2 = fmaxf(r2, 0.f); r3 = fmaxf(r3, 0.f);
        }
        float4 rv = make_float4(r0, r1, r2, r3);
        *reinterpret_cast<float4*>(&out[(size_t)n * 128 + c4]) = rv;
    }
}

extern "C" void kernel_launch(void* const* d_in, const int* in_sizes, int n_in,
                              void* d_out, int out_size, void* d_ws, size_t ws_size,
                              hipStream_t stream) {
    const float* x  = (const float*)d_in[0];
    const int*   ei = (const int*)d_in[1];
    const float* W1 = (const float*)d_in[2];
    const float* b1 = (const float*)d_in[3];
    const float* W2 = (const float*)d_in[4];
    const float* b2 = (const float*)d_in[5];
    const int* src = ei;             // edge_index[0]
    const int* dst = ei + N_EDGES;   // edge_index[1]
    float* out = (float*)d_out;

    char* ws = (char*)d_ws;
    unsigned* deg = (unsigned*)ws;                          // 400 KB
    float* dis    = (float*)(ws + 400000);                  // 400 KB
    float* h      = (float*)(ws + 800000);                  // 51.2 MB
    float* a      = (float*)(ws + 800000 + 51200000);       // 51.2 MB

    const size_t feat_bytes = (size_t)N_NODES * HID * sizeof(float);

    // degrees + normalization
    hipMemsetAsync(deg, 0, N_NODES * sizeof(unsigned), stream);
    k_count<<<2048, 256, 0, stream>>>(dst, deg, N_EDGES);
    k_dis<<<(N_NODES + 255) / 256, 256, 0, stream>>>(deg, dis, N_NODES);

    // ---- layer 1 ----
    k_gemm<<<(N_NODES + 63) / 64, 256, 0, stream>>>(x, W1, h, N_NODES, IN_CH);
    hipMemsetAsync(a, 0, feat_bytes, stream);
    k_scatter<<<4096, 256, 0, stream>>>(h, src, dst, dis, a, N_EDGES);
    k_finalize<<<4096, 256, 0, stream>>>(h, dis, b1, a, N_NODES, 1);

    // ---- layer 2 ----
    k_gemm<<<(N_NODES + 63) / 64, 256, 0, stream>>>(a, W2, h, N_NODES, HID);
    hipMemsetAsync(out, 0, feat_bytes, stream);
    k_scatter<<<4096, 256, 0, stream>>>(h, src, dst, dis, out, N_EDGES);
    k_finalize<<<4096, 256, 0, stream>>>(h, dis, b2, out, N_NODES, 0);
}

// Round 2
// 1118.159 us; speedup vs baseline: 9.9682x; 9.9682x over previous
//
#include <hip/hip_runtime.h>

#define N_NODES 100000
#define N_EDGES 3200000
#define IN_CH   384
#define HID     128
#define SCAN_NBLK ((N_NODES + 1023) / 1024)   // 98

// ---------------- degree count (in-degree, excl self-loop) ----------------
__global__ void k_count(const int* __restrict__ dst, unsigned* __restrict__ deg, int E) {
    int i = blockIdx.x * blockDim.x + threadIdx.x;
    int stride = gridDim.x * blockDim.x;
    for (; i < E; i += stride) atomicAdd(&deg[dst[i]], 1u);
}

__global__ void k_dis(const unsigned* __restrict__ deg, float* __restrict__ dis, int N) {
    int i = blockIdx.x * blockDim.x + threadIdx.x;
    if (i < N) dis[i] = rsqrtf((float)(deg[i] + 1u));  // +1 self-loop
}

// ---------------- two-level exclusive scan: deg -> rowptr ----------------
// level 1: per-block (1024 elems, 256 thr x 4) exclusive scan + block sums
__global__ __launch_bounds__(256) void k_scan1(const unsigned* __restrict__ deg,
                                               unsigned* __restrict__ rowptr,
                                               unsigned* __restrict__ bsum, int N) {
    __shared__ unsigned s[256];
    const int t = threadIdx.x;
    const int base = blockIdx.x * 1024 + t * 4;
    unsigned v[4], sum = 0;
#pragma unroll
    for (int i = 0; i < 4; i++) {
        v[i] = (base + i < N) ? deg[base + i] : 0u;
        sum += v[i];
    }
    s[t] = sum;
    __syncthreads();
    for (int off = 1; off < 256; off <<= 1) {
        unsigned x = s[t];
        unsigned y = (t >= off) ? s[t - off] : 0u;
        __syncthreads();
        s[t] = x + y;
        __syncthreads();
    }
    unsigned ex = s[t] - sum;   // exclusive prefix of this thread within block
    unsigned run = 0;
#pragma unroll
    for (int i = 0; i < 4; i++) {
        if (base + i < N) rowptr[base + i] = ex + run;
        run += v[i];
    }
    if (t == 255) bsum[blockIdx.x] = s[255];
}

// level 2: single block scans the block sums (exclusive, in place)
__global__ __launch_bounds__(128) void k_scan2(unsigned* __restrict__ bsum, int nb) {
    __shared__ unsigned s[128];
    const int t = threadIdx.x;
    unsigned orig = (t < nb) ? bsum[t] : 0u;
    s[t] = orig;
    __syncthreads();
    for (int off = 1; off < 128; off <<= 1) {
        unsigned x = s[t];
        unsigned y = (t >= off) ? s[t - off] : 0u;
        __syncthreads();
        s[t] = x + y;
        __syncthreads();
    }
    if (t < nb) bsum[t] = s[t] - orig;
}

// level 3: add block offsets; write rowptr[N] = E
__global__ __launch_bounds__(256) void k_scan3(unsigned* __restrict__ rowptr,
                                               const unsigned* __restrict__ bsum, int N, int E) {
    const int t = threadIdx.x;
    const int base = blockIdx.x * 1024 + t * 4;
    unsigned add = bsum[blockIdx.x];
#pragma unroll
    for (int i = 0; i < 4; i++)
        if (base + i < N) rowptr[base + i] += add;
    if (blockIdx.x == 0 && t == 0) rowptr[N] = (unsigned)E;
}

// ---------------- CSR fill: csr_src[rowptr[d] + cursor[d]++] = src[e] ----------------
__global__ void k_fill(const int* __restrict__ src, const int* __restrict__ dst,
                       const unsigned* __restrict__ rowptr, unsigned* __restrict__ cursor,
                       int* __restrict__ csr_src, int E) {
    int i = blockIdx.x * blockDim.x + threadIdx.x;
    int stride = gridDim.x * blockDim.x;
    for (; i < E; i += stride) {
        int d = dst[i];
        unsigned pos = rowptr[d] + atomicAdd(&cursor[d], 1u);
        csr_src[pos] = src[i];
    }
}

// ---------------- fp32 GEMM: C[M,128] = A[M,K] @ B[K,128] ----------------
__global__ __launch_bounds__(256) void k_gemm(const float* __restrict__ A,
                                              const float* __restrict__ B,
                                              float* __restrict__ C, int M, int K) {
    __shared__ float As[64][16];
    __shared__ float Bs[16][128];
    const int tid = threadIdx.x;
    const int tx = tid & 15;
    const int ty = tid >> 4;
    const int row0 = blockIdx.x * 64;

    float acc[4][8];
#pragma unroll
    for (int i = 0; i < 4; i++)
#pragma unroll
        for (int j = 0; j < 8; j++) acc[i][j] = 0.f;

    const int lrow = tid >> 2;
    const int lc4  = (tid & 3) * 4;

    for (int k0 = 0; k0 < K; k0 += 16) {
        int ar = row0 + lrow;
        float4 av = make_float4(0.f, 0.f, 0.f, 0.f);
        if (ar < M) av = *reinterpret_cast<const float4*>(&A[(size_t)ar * K + k0 + lc4]);
        *reinterpret_cast<float4*>(&As[lrow][lc4]) = av;
#pragma unroll
        for (int t = 0; t < 2; t++) {
            int f4 = tid + t * 256;
            int br = f4 >> 5;
            int bc = (f4 & 31) * 4;
            *reinterpret_cast<float4*>(&Bs[br][bc]) =
                *reinterpret_cast<const float4*>(&B[(size_t)(k0 + br) * 128 + bc]);
        }
        __syncthreads();
#pragma unroll
        for (int kk = 0; kk < 16; kk++) {
            float a[4];
#pragma unroll
            for (int i = 0; i < 4; i++) a[i] = As[ty + i * 16][kk];
            float4 b0 = *reinterpret_cast<const float4*>(&Bs[kk][tx * 8]);
            float4 b1 = *reinterpret_cast<const float4*>(&Bs[kk][tx * 8 + 4]);
            float b[8] = {b0.x, b0.y, b0.z, b0.w, b1.x, b1.y, b1.z, b1.w};
#pragma unroll
            for (int i = 0; i < 4; i++)
#pragma unroll
                for (int j = 0; j < 8; j++) acc[i][j] = fmaf(a[i], b[j], acc[i][j]);
        }
        __syncthreads();
    }
#pragma unroll
    for (int i = 0; i < 4; i++) {
        int r = row0 + ty + i * 16;
        if (r < M) {
            float4 c0 = make_float4(acc[i][0], acc[i][1], acc[i][2], acc[i][3]);
            float4 c1 = make_float4(acc[i][4], acc[i][5], acc[i][6], acc[i][7]);
            *reinterpret_cast<float4*>(&C[(size_t)r * 128 + tx * 8]) = c0;
            *reinterpret_cast<float4*>(&C[(size_t)r * 128 + tx * 8 + 4]) = c1;
        }
    }
}

// ---------------- aggregate: one wave per dst node, no atomics ----------------
// out[d] = dis[d] * ( sum_e dis[src_e]*h[src_e] + dis[d]*h[d] ) + bias  [, relu]
__global__ __launch_bounds__(256) void k_aggregate(const float* __restrict__ h,
                                                   const int* __restrict__ csr_src,
                                                   const unsigned* __restrict__ rowptr,
                                                   const float* __restrict__ dis,
                                                   const float* __restrict__ bias,
                                                   float* __restrict__ out, int N, int relu) {
    const int wave = (int)((blockIdx.x * blockDim.x + threadIdx.x) >> 6);
    const int lane = threadIdx.x & 63;
    if (wave >= N) return;
    const int d = wave;
    const unsigned beg = rowptr[d], end = rowptr[d + 1];
    const float dd = dis[d];

    float2 hv = reinterpret_cast<const float2*>(&h[(size_t)d * 128])[lane];
    float accx = dd * hv.x, accy = dd * hv.y;   // self-loop term

    for (unsigned e = beg; e < end; e++) {
        int s = csr_src[e];
        float ds = dis[s];
        float2 v = reinterpret_cast<const float2*>(&h[(size_t)s * 128])[lane];
        accx = fmaf(ds, v.x, accx);
        accy = fmaf(ds, v.y, accy);
    }
    float2 bv = reinterpret_cast<const float2*>(bias)[lane];
    float r0 = fmaf(dd, accx, bv.x);
    float r1 = fmaf(dd, accy, bv.y);
    if (relu) { r0 = fmaxf(r0, 0.f); r1 = fmaxf(r1, 0.f); }
    reinterpret_cast<float2*>(&out[(size_t)d * 128])[lane] = make_float2(r0, r1);
}

extern "C" void kernel_launch(void* const* d_in, const int* in_sizes, int n_in,
                              void* d_out, int out_size, void* d_ws, size_t ws_size,
                              hipStream_t stream) {
    const float* x  = (const float*)d_in[0];
    const int*   ei = (const int*)d_in[1];
    const float* b1 = (const float*)d_in[3];
    const float* W1 = (const float*)d_in[2];
    const float* W2 = (const float*)d_in[4];
    const float* b2 = (const float*)d_in[5];
    const int* src = ei;             // edge_index[0]
    const int* dst = ei + N_EDGES;   // edge_index[1]
    float* out = (float*)d_out;

    char* ws = (char*)d_ws;
    unsigned* deg    = (unsigned*)ws;                            // 400 KB (reused as cursor)
    float*    dis    = (float*)(ws + 400000);                    // 400 KB
    unsigned* rowptr = (unsigned*)(ws + 800000);                 // 400,004 B
    unsigned* bsum   = (unsigned*)(ws + 1200512);                // ~4 KB
    int*      csr    = (int*)(ws + 1204608);                     // 12.8 MB
    float*    h      = (float*)(ws + 1204608 + 12800000);        // 51.2 MB
    float*    a      = (float*)(ws + 1204608 + 12800000 + 51200000); // 51.2 MB

    // ---- degrees + normalization ----
    hipMemsetAsync(deg, 0, N_NODES * sizeof(unsigned), stream);
    k_count<<<2048, 256, 0, stream>>>(dst, deg, N_EDGES);
    k_dis<<<(N_NODES + 255) / 256, 256, 0, stream>>>(deg, dis, N_NODES);

    // ---- CSR by destination ----
    k_scan1<<<SCAN_NBLK, 256, 0, stream>>>(deg, rowptr, bsum, N_NODES);
    k_scan2<<<1, 128, 0, stream>>>(bsum, SCAN_NBLK);
    k_scan3<<<SCAN_NBLK, 256, 0, stream>>>(rowptr, bsum, N_NODES, N_EDGES);
    hipMemsetAsync(deg, 0, N_NODES * sizeof(unsigned), stream);   // deg -> cursor
    k_fill<<<4096, 256, 0, stream>>>(src, dst, rowptr, deg, csr, N_EDGES);

    // ---- layer 1 ----
    k_gemm<<<(N_NODES + 63) / 64, 256, 0, stream>>>(x, W1, h, N_NODES, IN_CH);
    k_aggregate<<<(N_NODES * 64 + 255) / 256, 256, 0, stream>>>(h, csr, rowptr, dis, b1, a, N_NODES, 1);

    // ---- layer 2 ----
    k_gemm<<<(N_NODES + 63) / 64, 256, 0, stream>>>(a, W2, h, N_NODES, HID);
    k_aggregate<<<(N_NODES * 64 + 255) / 256, 256, 0, stream>>>(h, csr, rowptr, dis, b2, out, N_NODES, 0);
}

// Round 3
// 959.111 us; speedup vs baseline: 11.6212x; 1.1658x over previous
//
#include <hip/hip_runtime.h>

#define N_NODES 100000
#define N_EDGES 3200000
#define IN_CH   384
#define HID     128
#define SCAN_NBLK ((N_NODES + 1023) / 1024)   // 98

// ---------------- degree count (in-degree, excl self-loop) ----------------
__global__ void k_count(const int* __restrict__ dst, unsigned* __restrict__ deg, int E4) {
    int i = blockIdx.x * blockDim.x + threadIdx.x;
    int stride = gridDim.x * blockDim.x;
    const int4* d4 = (const int4*)dst;
    for (; i < E4; i += stride) {
        int4 v = d4[i];
        atomicAdd(&deg[v.x], 1u);
        atomicAdd(&deg[v.y], 1u);
        atomicAdd(&deg[v.z], 1u);
        atomicAdd(&deg[v.w], 1u);
    }
}

__global__ void k_dis(const unsigned* __restrict__ deg, float* __restrict__ dis, int N) {
    int i = blockIdx.x * blockDim.x + threadIdx.x;
    if (i < N) dis[i] = rsqrtf((float)(deg[i] + 1u));  // +1 self-loop
}

// ---------------- two-level exclusive scan: deg -> rowptr ----------------
__global__ __launch_bounds__(256) void k_scan1(const unsigned* __restrict__ deg,
                                               unsigned* __restrict__ rowptr,
                                               unsigned* __restrict__ bsum, int N) {
    __shared__ unsigned s[256];
    const int t = threadIdx.x;
    const int base = blockIdx.x * 1024 + t * 4;
    unsigned v[4], sum = 0;
#pragma unroll
    for (int i = 0; i < 4; i++) {
        v[i] = (base + i < N) ? deg[base + i] : 0u;
        sum += v[i];
    }
    s[t] = sum;
    __syncthreads();
    for (int off = 1; off < 256; off <<= 1) {
        unsigned x = s[t];
        unsigned y = (t >= off) ? s[t - off] : 0u;
        __syncthreads();
        s[t] = x + y;
        __syncthreads();
    }
    unsigned ex = s[t] - sum;
    unsigned run = 0;
#pragma unroll
    for (int i = 0; i < 4; i++) {
        if (base + i < N) rowptr[base + i] = ex + run;
        run += v[i];
    }
    if (t == 255) bsum[blockIdx.x] = s[255];
}

__global__ __launch_bounds__(128) void k_scan2(unsigned* __restrict__ bsum, int nb) {
    __shared__ unsigned s[128];
    const int t = threadIdx.x;
    unsigned orig = (t < nb) ? bsum[t] : 0u;
    s[t] = orig;
    __syncthreads();
    for (int off = 1; off < 128; off <<= 1) {
        unsigned x = s[t];
        unsigned y = (t >= off) ? s[t - off] : 0u;
        __syncthreads();
        s[t] = x + y;
        __syncthreads();
    }
    if (t < nb) bsum[t] = s[t] - orig;
}

__global__ __launch_bounds__(256) void k_scan3(unsigned* __restrict__ rowptr,
                                               const unsigned* __restrict__ bsum, int N, int E) {
    const int t = threadIdx.x;
    const int base = blockIdx.x * 1024 + t * 4;
    unsigned add = bsum[blockIdx.x];
#pragma unroll
    for (int i = 0; i < 4; i++)
        if (base + i < N) rowptr[base + i] += add;
    if (blockIdx.x == 0 && t == 0) rowptr[N] = (unsigned)E;
}

// ---------------- CSR fill ----------------
__global__ void k_fill(const int* __restrict__ src, const int* __restrict__ dst,
                       const unsigned* __restrict__ rowptr, unsigned* __restrict__ cursor,
                       int* __restrict__ csr_src, int E4) {
    int i = blockIdx.x * blockDim.x + threadIdx.x;
    int stride = gridDim.x * blockDim.x;
    const int4* s4 = (const int4*)src;
    const int4* d4 = (const int4*)dst;
    for (; i < E4; i += stride) {
        int4 sv = s4[i];
        int4 dv = d4[i];
        unsigned p0 = rowptr[dv.x] + atomicAdd(&cursor[dv.x], 1u);
        csr_src[p0] = sv.x;
        unsigned p1 = rowptr[dv.y] + atomicAdd(&cursor[dv.y], 1u);
        csr_src[p1] = sv.y;
        unsigned p2 = rowptr[dv.z] + atomicAdd(&cursor[dv.z], 1u);
        csr_src[p2] = sv.z;
        unsigned p3 = rowptr[dv.w] + atomicAdd(&cursor[dv.w], 1u);
        csr_src[p3] = sv.w;
    }
}

// ---------------- fp32 GEMM: C[M,128] = A[M,K] @ B[K,128] ----------------
// 256 threads, tile 128x128, K-chunk 16, 8x8 outputs/thread (split 2x2 of 4x4)
__global__ __launch_bounds__(256) void k_gemm(const float* __restrict__ A,
                                              const float* __restrict__ B,
                                              float* __restrict__ C, int M, int K) {
    __shared__ float As[16][132];   // transposed: As[k][row]
    __shared__ float Bs[16][132];
    const int tid = threadIdx.x;
    const int tx = tid & 15;        // cols tx*4, 64+tx*4
    const int ty = tid >> 4;        // rows ty*4, 64+ty*4
    const int row0 = blockIdx.x * 128;

    float acc[2][2][4][4];
#pragma unroll
    for (int p = 0; p < 2; p++)
#pragma unroll
        for (int q = 0; q < 2; q++)
#pragma unroll
            for (int i = 0; i < 4; i++)
#pragma unroll
                for (int j = 0; j < 4; j++) acc[p][q][i][j] = 0.f;

    for (int k0 = 0; k0 < K; k0 += 16) {
        // stage A tile [128 rows x 16 k] transposed into As[k][row]
#pragma unroll
        for (int t = 0; t < 2; t++) {
            int f4 = tid + t * 256;
            int r = f4 >> 2;
            int c4 = (f4 & 3) * 4;
            int ar = row0 + r;
            float4 av = make_float4(0.f, 0.f, 0.f, 0.f);
            if (ar < M) av = *reinterpret_cast<const float4*>(&A[(size_t)ar * K + k0 + c4]);
            As[c4 + 0][r] = av.x;
            As[c4 + 1][r] = av.y;
            As[c4 + 2][r] = av.z;
            As[c4 + 3][r] = av.w;
        }
        // stage B tile [16 x 128]
#pragma unroll
        for (int t = 0; t < 2; t++) {
            int f4 = tid + t * 256;
            int br = f4 >> 5;
            int bc = (f4 & 31) * 4;
            *reinterpret_cast<float4*>(&Bs[br][bc]) =
                *reinterpret_cast<const float4*>(&B[(size_t)(k0 + br) * 128 + bc]);
        }
        __syncthreads();
#pragma unroll
        for (int kk = 0; kk < 16; kk++) {
            float4 a0 = *reinterpret_cast<const float4*>(&As[kk][ty * 4]);
            float4 a1 = *reinterpret_cast<const float4*>(&As[kk][64 + ty * 4]);
            float4 b0 = *reinterpret_cast<const float4*>(&Bs[kk][tx * 4]);
            float4 b1 = *reinterpret_cast<const float4*>(&Bs[kk][64 + tx * 4]);
            float af[2][4] = {{a0.x, a0.y, a0.z, a0.w}, {a1.x, a1.y, a1.z, a1.w}};
            float bf[2][4] = {{b0.x, b0.y, b0.z, b0.w}, {b1.x, b1.y, b1.z, b1.w}};
#pragma unroll
            for (int p = 0; p < 2; p++)
#pragma unroll
                for (int q = 0; q < 2; q++)
#pragma unroll
                    for (int i = 0; i < 4; i++)
#pragma unroll
                        for (int j = 0; j < 4; j++)
                            acc[p][q][i][j] = fmaf(af[p][i], bf[q][j], acc[p][q][i][j]);
        }
        __syncthreads();
    }
#pragma unroll
    for (int p = 0; p < 2; p++)
#pragma unroll
        for (int i = 0; i < 4; i++) {
            int r = row0 + p * 64 + ty * 4 + i;
            if (r < M) {
#pragma unroll
                for (int q = 0; q < 2; q++) {
                    float4 cv = make_float4(acc[p][q][i][0], acc[p][q][i][1],
                                            acc[p][q][i][2], acc[p][q][i][3]);
                    *reinterpret_cast<float4*>(&C[(size_t)r * 128 + q * 64 + tx * 4]) = cv;
                }
            }
        }
}

// ---------------- aggregate: one wave per dst node, unrolled x8 ----------------
__global__ __launch_bounds__(256) void k_aggregate(const float* __restrict__ h,
                                                   const int* __restrict__ csr_src,
                                                   const unsigned* __restrict__ rowptr,
                                                   const float* __restrict__ dis,
                                                   const float* __restrict__ bias,
                                                   float* __restrict__ out, int N, int relu) {
    const int wid = (int)((blockIdx.x * (blockDim.x >> 6)) + (threadIdx.x >> 6));
    const int d = __builtin_amdgcn_readfirstlane(wid);   // wave-uniform -> SGPR
    if (d >= N) return;
    const int lane = threadIdx.x & 63;
    const unsigned beg = rowptr[d], end = rowptr[d + 1];
    const float dd = dis[d];
    const float2* h2 = reinterpret_cast<const float2*>(h);

    float2 hv = h2[(size_t)d * 64 + lane];
    float ax = dd * hv.x, ay = dd * hv.y;   // self-loop term

    unsigned e = beg;
    for (; e + 8 <= end; e += 8) {
        int s[8];
        float w[8];
        float2 v[8];
#pragma unroll
        for (int u = 0; u < 8; u++) s[u] = csr_src[e + u];
#pragma unroll
        for (int u = 0; u < 8; u++) w[u] = dis[s[u]];
#pragma unroll
        for (int u = 0; u < 8; u++) v[u] = h2[(size_t)s[u] * 64 + lane];
#pragma unroll
        for (int u = 0; u < 8; u++) {
            ax = fmaf(w[u], v[u].x, ax);
            ay = fmaf(w[u], v[u].y, ay);
        }
    }
    for (; e < end; e++) {
        int s0 = csr_src[e];
        float w0 = dis[s0];
        float2 v0 = h2[(size_t)s0 * 64 + lane];
        ax = fmaf(w0, v0.x, ax);
        ay = fmaf(w0, v0.y, ay);
    }
    float2 bv = reinterpret_cast<const float2*>(bias)[lane];
    float r0 = fmaf(dd, ax, bv.x);
    float r1 = fmaf(dd, ay, bv.y);
    if (relu) { r0 = fmaxf(r0, 0.f); r1 = fmaxf(r1, 0.f); }
    reinterpret_cast<float2*>(out)[(size_t)d * 64 + lane] = make_float2(r0, r1);
}

extern "C" void kernel_launch(void* const* d_in, const int* in_sizes, int n_in,
                              void* d_out, int out_size, void* d_ws, size_t ws_size,
                              hipStream_t stream) {
    const float* x  = (const float*)d_in[0];
    const int*   ei = (const int*)d_in[1];
    const float* W1 = (const float*)d_in[2];
    const float* b1 = (const float*)d_in[3];
    const float* W2 = (const float*)d_in[4];
    const float* b2 = (const float*)d_in[5];
    const int* src = ei;             // edge_index[0]
    const int* dst = ei + N_EDGES;   // edge_index[1]
    float* out = (float*)d_out;

    char* ws = (char*)d_ws;
    unsigned* deg    = (unsigned*)ws;                            // 400 KB (reused as cursor)
    float*    dis    = (float*)(ws + 400000);                    // 400 KB
    unsigned* rowptr = (unsigned*)(ws + 800000);                 // 400,004 B
    unsigned* bsum   = (unsigned*)(ws + 1200512);                // ~4 KB
    int*      csr    = (int*)(ws + 1204608);                     // 12.8 MB
    float*    h      = (float*)(ws + 1204608 + 12800000);        // 51.2 MB
    float*    a      = (float*)(ws + 1204608 + 12800000 + 51200000); // 51.2 MB

    // ---- degrees + normalization ----
    hipMemsetAsync(deg, 0, N_NODES * sizeof(unsigned), stream);
    k_count<<<2048, 256, 0, stream>>>(dst, deg, N_EDGES / 4);
    k_dis<<<(N_NODES + 255) / 256, 256, 0, stream>>>(deg, dis, N_NODES);

    // ---- CSR by destination ----
    k_scan1<<<SCAN_NBLK, 256, 0, stream>>>(deg, rowptr, bsum, N_NODES);
    k_scan2<<<1, 128, 0, stream>>>(bsum, SCAN_NBLK);
    k_scan3<<<SCAN_NBLK, 256, 0, stream>>>(rowptr, bsum, N_NODES, N_EDGES);
    hipMemsetAsync(deg, 0, N_NODES * sizeof(unsigned), stream);   // deg -> cursor
    k_fill<<<2048, 256, 0, stream>>>(src, dst, rowptr, deg, csr, N_EDGES / 4);

    // ---- layer 1 ----
    k_gemm<<<(N_NODES + 127) / 128, 256, 0, stream>>>(x, W1, h, N_NODES, IN_CH);
    k_aggregate<<<(N_NODES * 64 + 255) / 256, 256, 0, stream>>>(h, csr, rowptr, dis, b1, a, N_NODES, 1);

    // ---- layer 2 ----
    k_gemm<<<(N_NODES + 127) / 128, 256, 0, stream>>>(a, W2, h, N_NODES, HID);
    k_aggregate<<<(N_NODES * 64 + 255) / 256, 256, 0, stream>>>(h, csr, rowptr, dis, b2, out, N_NODES, 0);
}

// Round 4
// 747.248 us; speedup vs baseline: 14.9160x; 1.2835x over previous
//
#include <hip/hip_runtime.h>

#define N_NODES 100000
#define N_EDGES 3200000
#define IN_CH   384
#define HID     128
#define SCAN_NBLK ((N_NODES + 1023) / 1024)   // 98

static __device__ __forceinline__ unsigned short f2bf(float f) {
    unsigned u = __float_as_uint(f);
    unsigned r = (u + 0x7fffu + ((u >> 16) & 1u)) >> 16;   // RTN-even
    return (unsigned short)r;
}

// ---------------- degree count (in-degree, excl self-loop) ----------------
__global__ void k_count(const int* __restrict__ dst, unsigned* __restrict__ deg, int E4) {
    int i = blockIdx.x * blockDim.x + threadIdx.x;
    int stride = gridDim.x * blockDim.x;
    const int4* d4 = (const int4*)dst;
    for (; i < E4; i += stride) {
        int4 v = d4[i];
        atomicAdd(&deg[v.x], 1u);
        atomicAdd(&deg[v.y], 1u);
        atomicAdd(&deg[v.z], 1u);
        atomicAdd(&deg[v.w], 1u);
    }
}

__global__ void k_dis(const unsigned* __restrict__ deg, float* __restrict__ dis, int N) {
    int i = blockIdx.x * blockDim.x + threadIdx.x;
    if (i < N) dis[i] = rsqrtf((float)(deg[i] + 1u));  // +1 self-loop
}

// ---------------- two-level exclusive scan: deg -> rowptr ----------------
__global__ __launch_bounds__(256) void k_scan1(const unsigned* __restrict__ deg,
                                               unsigned* __restrict__ rowptr,
                                               unsigned* __restrict__ bsum, int N) {
    __shared__ unsigned s[256];
    const int t = threadIdx.x;
    const int base = blockIdx.x * 1024 + t * 4;
    unsigned v[4], sum = 0;
#pragma unroll
    for (int i = 0; i < 4; i++) {
        v[i] = (base + i < N) ? deg[base + i] : 0u;
        sum += v[i];
    }
    s[t] = sum;
    __syncthreads();
    for (int off = 1; off < 256; off <<= 1) {
        unsigned x = s[t];
        unsigned y = (t >= off) ? s[t - off] : 0u;
        __syncthreads();
        s[t] = x + y;
        __syncthreads();
    }
    unsigned ex = s[t] - sum;
    unsigned run = 0;
#pragma unroll
    for (int i = 0; i < 4; i++) {
        if (base + i < N) rowptr[base + i] = ex + run;
        run += v[i];
    }
    if (t == 255) bsum[blockIdx.x] = s[255];
}

__global__ __launch_bounds__(128) void k_scan2(unsigned* __restrict__ bsum, int nb) {
    __shared__ unsigned s[128];
    const int t = threadIdx.x;
    unsigned orig = (t < nb) ? bsum[t] : 0u;
    s[t] = orig;
    __syncthreads();
    for (int off = 1; off < 128; off <<= 1) {
        unsigned x = s[t];
        unsigned y = (t >= off) ? s[t - off] : 0u;
        __syncthreads();
        s[t] = x + y;
        __syncthreads();
    }
    if (t < nb) bsum[t] = s[t] - orig;
}

__global__ __launch_bounds__(256) void k_scan3(unsigned* __restrict__ rowptr,
                                               const unsigned* __restrict__ bsum, int N, int E) {
    const int t = threadIdx.x;
    const int base = blockIdx.x * 1024 + t * 4;
    unsigned add = bsum[blockIdx.x];
#pragma unroll
    for (int i = 0; i < 4; i++)
        if (base + i < N) rowptr[base + i] += add;
    if (blockIdx.x == 0 && t == 0) rowptr[N] = (unsigned)E;
}

// ---------------- CSR fill ----------------
__global__ void k_fill(const int* __restrict__ src, const int* __restrict__ dst,
                       const unsigned* __restrict__ rowptr, unsigned* __restrict__ cursor,
                       int* __restrict__ csr_src, int E4) {
    int i = blockIdx.x * blockDim.x + threadIdx.x;
    int stride = gridDim.x * blockDim.x;
    const int4* s4 = (const int4*)src;
    const int4* d4 = (const int4*)dst;
    for (; i < E4; i += stride) {
        int4 sv = s4[i];
        int4 dv = d4[i];
        unsigned p0 = rowptr[dv.x] + atomicAdd(&cursor[dv.x], 1u);
        csr_src[p0] = sv.x;
        unsigned p1 = rowptr[dv.y] + atomicAdd(&cursor[dv.y], 1u);
        csr_src[p1] = sv.y;
        unsigned p2 = rowptr[dv.z] + atomicAdd(&cursor[dv.z], 1u);
        csr_src[p2] = sv.z;
        unsigned p3 = rowptr[dv.w] + atomicAdd(&cursor[dv.w], 1u);
        csr_src[p3] = sv.w;
    }
}

// ---------------- fp32 GEMM -> bf16 out: C[M,128] = A[M,K] @ B[K,128] ----------------
// 256 threads, tile 128x128, K-chunk 16, 8x8 outputs/thread (split 2x2 of 4x4)
__global__ __launch_bounds__(256) void k_gemm(const float* __restrict__ A,
                                              const float* __restrict__ B,
                                              unsigned short* __restrict__ C, int M, int K) {
    __shared__ float As[16][132];   // transposed: As[k][row]
    __shared__ float Bs[16][132];
    const int tid = threadIdx.x;
    const int tx = tid & 15;        // cols tx*4, 64+tx*4
    const int ty = tid >> 4;        // rows ty*4, 64+ty*4
    const int row0 = blockIdx.x * 128;

    float acc[2][2][4][4];
#pragma unroll
    for (int p = 0; p < 2; p++)
#pragma unroll
        for (int q = 0; q < 2; q++)
#pragma unroll
            for (int i = 0; i < 4; i++)
#pragma unroll
                for (int j = 0; j < 4; j++) acc[p][q][i][j] = 0.f;

    for (int k0 = 0; k0 < K; k0 += 16) {
#pragma unroll
        for (int t = 0; t < 2; t++) {
            int f4 = tid + t * 256;
            int r = f4 >> 2;
            int c4 = (f4 & 3) * 4;
            int ar = row0 + r;
            float4 av = make_float4(0.f, 0.f, 0.f, 0.f);
            if (ar < M) av = *reinterpret_cast<const float4*>(&A[(size_t)ar * K + k0 + c4]);
            As[c4 + 0][r] = av.x;
            As[c4 + 1][r] = av.y;
            As[c4 + 2][r] = av.z;
            As[c4 + 3][r] = av.w;
        }
#pragma unroll
        for (int t = 0; t < 2; t++) {
            int f4 = tid + t * 256;
            int br = f4 >> 5;
            int bc = (f4 & 31) * 4;
            *reinterpret_cast<float4*>(&Bs[br][bc]) =
                *reinterpret_cast<const float4*>(&B[(size_t)(k0 + br) * 128 + bc]);
        }
        __syncthreads();
#pragma unroll
        for (int kk = 0; kk < 16; kk++) {
            float4 a0 = *reinterpret_cast<const float4*>(&As[kk][ty * 4]);
            float4 a1 = *reinterpret_cast<const float4*>(&As[kk][64 + ty * 4]);
            float4 b0 = *reinterpret_cast<const float4*>(&Bs[kk][tx * 4]);
            float4 b1 = *reinterpret_cast<const float4*>(&Bs[kk][64 + tx * 4]);
            float af[2][4] = {{a0.x, a0.y, a0.z, a0.w}, {a1.x, a1.y, a1.z, a1.w}};
            float bf[2][4] = {{b0.x, b0.y, b0.z, b0.w}, {b1.x, b1.y, b1.z, b1.w}};
#pragma unroll
            for (int p = 0; p < 2; p++)
#pragma unroll
                for (int q = 0; q < 2; q++)
#pragma unroll
                    for (int i = 0; i < 4; i++)
#pragma unroll
                        for (int j = 0; j < 4; j++)
                            acc[p][q][i][j] = fmaf(af[p][i], bf[q][j], acc[p][q][i][j]);
        }
        __syncthreads();
    }
#pragma unroll
    for (int p = 0; p < 2; p++)
#pragma unroll
        for (int i = 0; i < 4; i++) {
            int r = row0 + p * 64 + ty * 4 + i;
            if (r < M) {
#pragma unroll
                for (int q = 0; q < 2; q++) {
                    ushort4 cv;
                    cv.x = f2bf(acc[p][q][i][0]);
                    cv.y = f2bf(acc[p][q][i][1]);
                    cv.z = f2bf(acc[p][q][i][2]);
                    cv.w = f2bf(acc[p][q][i][3]);
                    *reinterpret_cast<ushort4*>(&C[(size_t)r * 128 + q * 64 + tx * 4]) = cv;
                }
            }
        }
}

// ---------------- aggregate: one wave per dst node, bf16 gather, unrolled x8 ----------------
__global__ __launch_bounds__(256) void k_aggregate(const unsigned short* __restrict__ h,
                                                   const int* __restrict__ csr_src,
                                                   const unsigned* __restrict__ rowptr,
                                                   const float* __restrict__ dis,
                                                   const float* __restrict__ bias,
                                                   float* __restrict__ out, int N, int relu) {
    const int wid = (int)((blockIdx.x * (blockDim.x >> 6)) + (threadIdx.x >> 6));
    const int d = __builtin_amdgcn_readfirstlane(wid);   // wave-uniform -> SGPR
    if (d >= N) return;
    const int lane = threadIdx.x & 63;
    const unsigned beg = rowptr[d], end = rowptr[d + 1];
    const float dd = dis[d];
    const unsigned* h1 = reinterpret_cast<const unsigned*>(h);  // 64 dwords/row = 2 bf16 each

    unsigned hv = h1[(size_t)d * 64 + lane];
    float ax = dd * __uint_as_float(hv << 16);           // ch 2*lane
    float ay = dd * __uint_as_float(hv & 0xffff0000u);   // ch 2*lane+1

    unsigned e = beg;
    for (; e + 8 <= end; e += 8) {
        int s[8];
        float w[8];
        unsigned v[8];
#pragma unroll
        for (int u = 0; u < 8; u++) s[u] = csr_src[e + u];
#pragma unroll
        for (int u = 0; u < 8; u++) w[u] = dis[s[u]];
#pragma unroll
        for (int u = 0; u < 8; u++) v[u] = h1[(size_t)s[u] * 64 + lane];
#pragma unroll
        for (int u = 0; u < 8; u++) {
            ax = fmaf(w[u], __uint_as_float(v[u] << 16), ax);
            ay = fmaf(w[u], __uint_as_float(v[u] & 0xffff0000u), ay);
        }
    }
    for (; e < end; e++) {
        int s0 = csr_src[e];
        float w0 = dis[s0];
        unsigned v0 = h1[(size_t)s0 * 64 + lane];
        ax = fmaf(w0, __uint_as_float(v0 << 16), ax);
        ay = fmaf(w0, __uint_as_float(v0 & 0xffff0000u), ay);
    }
    float2 bv = reinterpret_cast<const float2*>(bias)[lane];
    float r0 = fmaf(dd, ax, bv.x);
    float r1 = fmaf(dd, ay, bv.y);
    if (relu) { r0 = fmaxf(r0, 0.f); r1 = fmaxf(r1, 0.f); }
    reinterpret_cast<float2*>(out)[(size_t)d * 64 + lane] = make_float2(r0, r1);
}

extern "C" void kernel_launch(void* const* d_in, const int* in_sizes, int n_in,
                              void* d_out, int out_size, void* d_ws, size_t ws_size,
                              hipStream_t stream) {
    const float* x  = (const float*)d_in[0];
    const int*   ei = (const int*)d_in[1];
    const float* W1 = (const float*)d_in[2];
    const float* b1 = (const float*)d_in[3];
    const float* W2 = (const float*)d_in[4];
    const float* b2 = (const float*)d_in[5];
    const int* src = ei;             // edge_index[0]
    const int* dst = ei + N_EDGES;   // edge_index[1]
    float* out = (float*)d_out;

    char* ws = (char*)d_ws;
    unsigned*       deg    = (unsigned*)ws;                          // 400 KB (reused as cursor)
    float*          dis    = (float*)(ws + 400000);                  // 400 KB
    unsigned*       rowptr = (unsigned*)(ws + 800000);               // 400,004 B
    unsigned*       bsum   = (unsigned*)(ws + 1200512);              // ~4 KB
    int*            csr    = (int*)(ws + 1204608);                   // 12.8 MB
    unsigned short* hbf    = (unsigned short*)(ws + 1204608 + 12800000);          // 25.6 MB
    float*          a      = (float*)(ws + 1204608 + 12800000 + 25600000);        // 51.2 MB

    // ---- degrees + normalization ----
    hipMemsetAsync(deg, 0, N_NODES * sizeof(unsigned), stream);
    k_count<<<2048, 256, 0, stream>>>(dst, deg, N_EDGES / 4);
    k_dis<<<(N_NODES + 255) / 256, 256, 0, stream>>>(deg, dis, N_NODES);

    // ---- CSR by destination ----
    k_scan1<<<SCAN_NBLK, 256, 0, stream>>>(deg, rowptr, bsum, N_NODES);
    k_scan2<<<1, 128, 0, stream>>>(bsum, SCAN_NBLK);
    k_scan3<<<SCAN_NBLK, 256, 0, stream>>>(rowptr, bsum, N_NODES, N_EDGES);
    hipMemsetAsync(deg, 0, N_NODES * sizeof(unsigned), stream);   // deg -> cursor
    k_fill<<<2048, 256, 0, stream>>>(src, dst, rowptr, deg, csr, N_EDGES / 4);

    // ---- layer 1 ----
    k_gemm<<<(N_NODES + 127) / 128, 256, 0, stream>>>(x, W1, hbf, N_NODES, IN_CH);
    k_aggregate<<<(N_NODES * 64 + 255) / 256, 256, 0, stream>>>(hbf, csr, rowptr, dis, b1, a, N_NODES, 1);

    // ---- layer 2 ----
    k_gemm<<<(N_NODES + 127) / 128, 256, 0, stream>>>(a, W2, hbf, N_NODES, HID);
    k_aggregate<<<(N_NODES * 64 + 255) / 256, 256, 0, stream>>>(hbf, csr, rowptr, dis, b2, out, N_NODES, 0);
}